// Round 6
// baseline (540.591 us; speedup 1.0000x reference)
//
#include <hip/hip_runtime.h>
#include <hip/hip_bf16.h>
#include <math.h>

#define N_NODES 8192
#define IN_F    512
#define OUT_F   128
#define LRELU_A 0.2f
#define EPS_BN  1e-5f
#define MSH     40.0f                // static softmax shift (upper bound on lrelu(max s1+max s2))
#define NSPLIT  16
#define JSPAN   (N_NODES / NSPLIT)   // 512
#define TILE_I  64
#define CH      128                  // j per prefetch chunk (4 MFMA K-steps)
#define HSTR    520                  // LDS row stride in shorts (512 + 8 pad)

typedef unsigned short u16;
typedef unsigned int   u32;
typedef __attribute__((ext_vector_type(8))) short  short8;
typedef __attribute__((ext_vector_type(4))) float  floatx4;

__device__ __forceinline__ u16 f2bf_rtn(float x) {
    u32 u = __float_as_uint(x);
    return (u16)((u + 0x7fffu + ((u >> 16) & 1u)) >> 16);
}

// ---------------- h = input @ hamilton(W); emit hT bf16 + s1/s2; zero cs/cq ----------------
// grid 512 x 256 thr; block = 16 rows x 128 cols; thread = 1 row x 8 cols.
__global__ __launch_bounds__(256) void k_h(const float* __restrict__ inp, const float* __restrict__ W,
                                           const float* __restrict__ a,
                                           u16* __restrict__ hT, float* __restrict__ s1, float* __restrict__ s2,
                                           float* __restrict__ cs, float* __restrict__ cq) {
    __shared__ float s1b[16], s2b[16];
    const int t = threadIdx.x;
    if (t < 16) { s1b[t] = 0.f; s2b[t] = 0.f; }
    if (blockIdx.x == 0 && t < OUT_F) { cs[t] = 0.f; cq[t] = 0.f; }
    __syncthreads();
    const int rg = t >> 4, cg = t & 15;
    const int r = blockIdx.x * 16 + rg;
    const int b = cg >> 2, cc0 = (cg & 3) * 8;
    const u32 NEGMASK = 0x284Eu;     // bit (b*4+p) set => sign -1
    float acc[8];
#pragma unroll
    for (int q = 0; q < 8; q++) acc[q] = 0.f;
    const float* row = inp + (size_t)r * IN_F;
    for (int k8 = 0; k8 < IN_F; k8 += 8) {
        const int p = k8 >> 7;
        const float sg = (NEGMASK >> (b * 4 + p)) & 1u ? -1.f : 1.f;
        const float* wbase = W + (b ^ p) * 32 + cc0;
        float4 x0 = *(const float4*)(row + k8);
        float4 x1 = *(const float4*)(row + k8 + 4);
        float xv[8] = {x0.x, x0.y, x0.z, x0.w, x1.x, x1.y, x1.z, x1.w};
#pragma unroll
        for (int dk = 0; dk < 8; dk++) {
            const int q = (k8 + dk) & 127;
            const float* wp = wbase + q * 128;
            float4 w0 = *(const float4*)wp;
            float4 w1 = *(const float4*)(wp + 4);
            const float av = xv[dk] * sg;
            acc[0] += av * w0.x; acc[1] += av * w0.y; acc[2] += av * w0.z; acc[3] += av * w0.w;
            acc[4] += av * w1.x; acc[5] += av * w1.y; acc[6] += av * w1.z; acc[7] += av * w1.w;
        }
    }
    float s1p = 0.f, s2p = 0.f;
#pragma unroll
    for (int q = 0; q < 8; q++) {
        const int c = (cg << 3) + q;
        hT[(size_t)c * N_NODES + r] = f2bf_rtn(acc[q]);
        s1p += acc[q] * a[c];
        s2p += acc[q] * a[OUT_F + c];
    }
    atomicAdd(&s1b[rg], s1p);
    atomicAdd(&s2b[rg], s2p);
    __syncthreads();
    if (t < 16) { s1[blockIdx.x * 16 + t] = s1b[t]; s2[blockIdx.x * 16 + t] = s2b[t]; }
}

// ---------------- MFMA masked-softmax attention: barrier-free streaming j-loop ----------------
// grid (128, NSPLIT) x 256 thr (4 waves). Block: 64 i x 128 c over JSPAN=512 j.
// hT slice staged ONCE (130 KB LDS); adj streams to registers (1 chunk prefetch); no per-chunk barriers.
__global__ __launch_bounds__(256) void k_att(const int* __restrict__ adj, const u16* __restrict__ hT,
                                             const float* __restrict__ s1, const float* __restrict__ s2,
                                             float* __restrict__ Opart, float* __restrict__ Lpart) {
    __shared__ u16 hs[128 * HSTR];    // 133120 B
    __shared__ float s2s[JSPAN];      // 2048 B
    const int t = threadIdx.x;
    const int lane = t & 63, wid = t >> 6;
    const int quad = lane >> 4, n = lane & 15;
    const int i0 = blockIdx.x * TILE_I;
    const int jbase = blockIdx.y * JSPAN;
    const int i_lane = i0 + wid * 16 + n;       // A-frag m index
    const float s1v = s1[i_lane];

    if (t < 128) *(float4*)&s2s[t * 4] = *(const float4*)&s2[jbase + t * 4];
    // stage hT slice: 128 c-rows x 512 shorts; thread t -> row t>>1, half (t&1)*256 shorts
    {
        const int cr = t >> 1, off = (t & 1) * 256;
        const u16* src = hT + (size_t)cr * N_NODES + jbase + off;
        u16* dst = &hs[cr * HSTR + off];
#pragma unroll
        for (int v = 0; v < 32; v++)
            *(uint4*)(dst + v * 8) = *(const uint4*)(src + v * 8);
    }

    floatx4 acc[8];
#pragma unroll
    for (int ct = 0; ct < 8; ct++) acc[ct] = (floatx4){0.f, 0.f, 0.f, 0.f};
    float Lacc = 0.f;

    const int* adjp = adj + (size_t)i_lane * N_NODES + jbase;
    uint4 P[8];
#pragma unroll
    for (int ks = 0; ks < 4; ks++) {
        P[2 * ks]     = *(const uint4*)(adjp + ks * 32 + quad * 8);
        P[2 * ks + 1] = *(const uint4*)(adjp + ks * 32 + quad * 8 + 4);
    }
    __syncthreads();   // the ONLY barrier

#pragma unroll
    for (int k = 0; k < JSPAN / CH; k++) {       // 4 chunks, no barriers
        uint4 C[8];
#pragma unroll
        for (int v = 0; v < 8; v++) C[v] = P[v];
        if (k + 1 < JSPAN / CH) {
            const int* ap = adjp + (k + 1) * CH;
#pragma unroll
            for (int ks = 0; ks < 4; ks++) {
                P[2 * ks]     = *(const uint4*)(ap + ks * 32 + quad * 8);
                P[2 * ks + 1] = *(const uint4*)(ap + ks * 32 + quad * 8 + 4);
            }
        }
        short8 fa[4];
#pragma unroll
        for (int ks = 0; ks < 4; ks++) {
            const int jl = k * CH + ks * 32 + quad * 8;
            float4 sa = *(const float4*)&s2s[jl];
            float4 sb = *(const float4*)&s2s[jl + 4];
            const float sv[8] = {sa.x, sa.y, sa.z, sa.w, sb.x, sb.y, sb.z, sb.w};
            const u32 am[8] = {C[2*ks].x, C[2*ks].y, C[2*ks].z, C[2*ks].w,
                               C[2*ks+1].x, C[2*ks+1].y, C[2*ks+1].z, C[2*ks+1].w};
#pragma unroll
            for (int jj = 0; jj < 8; jj++) {
                float sc = s1v + sv[jj];
                sc = fmaxf(sc, LRELU_A * sc);
                float w = ((int)am[jj] > 0) ? __expf(sc - MSH) : 0.f;
                Lacc += w;
                fa[ks][jj] = (short)f2bf_rtn(w);
            }
        }
#pragma unroll
        for (int ks = 0; ks < 4; ks++) {
#pragma unroll
            for (int ct = 0; ct < 8; ct++) {
                short8 fb = *(const short8*)&hs[(ct * 16 + n) * HSTR + k * CH + ks * 32 + quad * 8];
                acc[ct] = __builtin_amdgcn_mfma_f32_16x16x32_bf16(fa[ks], fb, acc[ct], 0, 0, 0);
            }
        }
    }

    // L row-sum across quads (each lane's j's belong to row i_lane)
    Lacc += __shfl_xor(Lacc, 16, 64);
    Lacc += __shfl_xor(Lacc, 32, 64);
    if (lane < 16)
        Lpart[(size_t)blockIdx.y * N_NODES + i_lane] = Lacc;

    // store O partials (C layout: row = quad*4+reg, col = n)
    const size_t obase = (size_t)blockIdx.y * N_NODES * OUT_F;
#pragma unroll
    for (int ct = 0; ct < 8; ct++) {
#pragma unroll
        for (int r = 0; r < 4; r++) {
            const int i = i0 + wid * 16 + quad * 4 + r;
            Opart[obase + (size_t)i * OUT_F + ct * 16 + n] = acc[ct][r];
        }
    }
}

// ---------------- combine partials, normalize, column stats via atomics ----------------
// grid 512 x 256 thr; block = 16 i-rows
__global__ __launch_bounds__(256) void k_comb(const float* __restrict__ Opart, const float* __restrict__ Lpart,
                                              float* __restrict__ hp, float* __restrict__ cs, float* __restrict__ cq) {
    const int t = threadIdx.x;
    const int c = t & 127, half = t >> 7;
    const int ibase = blockIdx.x * 16;
    float sv = 0.f, sq = 0.f;
    for (int k = 0; k < 8; k++) {
        const int i = ibase + half + (k << 1);
        float o = 0.f, L = 0.f;
#pragma unroll
        for (int s = 0; s < NSPLIT; s++) {
            o += Opart[((size_t)s * N_NODES + i) * OUT_F + c];
            L += Lpart[(size_t)s * N_NODES + i];
        }
        float v = L > 0.f ? o / L : 0.f;
        hp[(size_t)i * OUT_F + c] = v;
        sv += v; sq += v * v;
    }
    __shared__ float red[256];
    red[t] = sv; __syncthreads();
    if (half == 0) atomicAdd(&cs[c], sv + red[t + 128]);
    __syncthreads(); red[t] = sq; __syncthreads();
    if (half == 0) atomicAdd(&cq[c], sq + red[t + 128]);
}

// ---------------- batchnorm + elu + f32 out ----------------
__global__ __launch_bounds__(256) void k_bn(const float* __restrict__ hp, const float* __restrict__ cs,
                                            const float* __restrict__ cq, const float* __restrict__ gamma,
                                            const float* __restrict__ beta, float* __restrict__ out) {
    const int idx = blockIdx.x * 256 + threadIdx.x;   // 1M
    const int c = idx & 127;
    const float mean = cs[c] * (1.f / N_NODES);
    const float var  = cq[c] * (1.f / N_NODES) - mean * mean;
    float x = (hp[idx] - mean) * rsqrtf(var + EPS_BN) * gamma[c] + beta[c];
    x = x > 0.f ? x : expm1f(x);
    out[idx] = x;
}

extern "C" void kernel_launch(void* const* d_in, const int* in_sizes, int n_in,
                              void* d_out, int out_size, void* d_ws, size_t ws_size,
                              hipStream_t stream) {
    (void)in_sizes; (void)n_in; (void)out_size; (void)ws_size;
    const float* inp   = (const float*)d_in[0];
    const int*   adj   = (const int*)d_in[1];
    const float* W     = (const float*)d_in[2];
    const float* a     = (const float*)d_in[3];
    const float* gamma = (const float*)d_in[4];
    const float* beta  = (const float*)d_in[5];
    float* out = (float*)d_out;

    char* wsb = (char*)d_ws;
    u16*   hT  = (u16*)wsb;    wsb += (size_t)OUT_F * N_NODES * 2;            // 2 MB
    float* s1  = (float*)wsb;  wsb += N_NODES * 4;
    float* s2  = (float*)wsb;  wsb += N_NODES * 4;
    float* Op  = (float*)wsb;  wsb += (size_t)NSPLIT * N_NODES * OUT_F * 4;   // 64 MB
    float* Lp  = (float*)wsb;  wsb += (size_t)NSPLIT * N_NODES * 4;
    float* hp  = (float*)wsb;  wsb += (size_t)N_NODES * OUT_F * 4;            // 4 MB
    float* cs  = (float*)wsb;  wsb += OUT_F * 4;
    float* cq  = (float*)wsb;  wsb += OUT_F * 4;

    hipLaunchKernelGGL(k_h,    dim3(512), dim3(256), 0, stream, inp, W, a, hT, s1, s2, cs, cq);
    hipLaunchKernelGGL(k_att,  dim3(128, NSPLIT), dim3(256), 0, stream, adj, hT, s1, s2, Op, Lp);
    hipLaunchKernelGGL(k_comb, dim3(512), dim3(256), 0, stream, Op, Lp, hp, cs, cq);
    hipLaunchKernelGGL(k_bn,   dim3(4096), dim3(256), 0, stream, hp, cs, cq, gamma, beta, out);
}

// Round 7
// 530.580 us; speedup vs baseline: 1.0189x; 1.0189x over previous
//
#include <hip/hip_runtime.h>
#include <hip/hip_bf16.h>
#include <math.h>

#define N_NODES 8192
#define IN_F    512
#define OUT_F   128
#define LRELU_A 0.2f
#define EPS_BN  1e-5f
#define MSH     40.0f                // static softmax shift (upper bound on lrelu(max s1+max s2))
#define NSPLIT  16
#define JSPAN   (N_NODES / NSPLIT)   // 512
#define TILE_I  128                  // 8 waves x 16 rows
#define CH      128                  // j per prefetch chunk (4 MFMA K-steps)
#define HSTR    520                  // LDS row stride in shorts (512 + 8 pad)

typedef unsigned short u16;
typedef unsigned int   u32;
typedef __attribute__((ext_vector_type(8))) short  short8;
typedef __attribute__((ext_vector_type(4))) float  floatx4;

__device__ __forceinline__ u16 f2bf_rtn(float x) {
    u32 u = __float_as_uint(x);
    return (u16)((u + 0x7fffu + ((u >> 16) & 1u)) >> 16);
}

// ---------------- h = input @ hamilton(W); emit hT bf16 + s1/s2; zero cs/cq ----------------
// grid 512 x 256 thr; block = 16 rows x 128 cols; thread = 1 row x 8 cols.
__global__ __launch_bounds__(256) void k_h(const float* __restrict__ inp, const float* __restrict__ W,
                                           const float* __restrict__ a,
                                           u16* __restrict__ hT, float* __restrict__ s1, float* __restrict__ s2,
                                           float* __restrict__ cs, float* __restrict__ cq) {
    __shared__ float s1b[16], s2b[16];
    const int t = threadIdx.x;
    if (t < 16) { s1b[t] = 0.f; s2b[t] = 0.f; }
    if (blockIdx.x == 0 && t < OUT_F) { cs[t] = 0.f; cq[t] = 0.f; }
    __syncthreads();
    const int rg = t >> 4, cg = t & 15;
    const int r = blockIdx.x * 16 + rg;
    const int b = cg >> 2, cc0 = (cg & 3) * 8;
    const u32 NEGMASK = 0x284Eu;     // bit (b*4+p) set => sign -1
    float acc[8];
#pragma unroll
    for (int q = 0; q < 8; q++) acc[q] = 0.f;
    const float* row = inp + (size_t)r * IN_F;
    for (int k8 = 0; k8 < IN_F; k8 += 8) {
        const int p = k8 >> 7;
        const float sg = (NEGMASK >> (b * 4 + p)) & 1u ? -1.f : 1.f;
        const float* wbase = W + (b ^ p) * 32 + cc0;
        float4 x0 = *(const float4*)(row + k8);
        float4 x1 = *(const float4*)(row + k8 + 4);
        float xv[8] = {x0.x, x0.y, x0.z, x0.w, x1.x, x1.y, x1.z, x1.w};
#pragma unroll
        for (int dk = 0; dk < 8; dk++) {
            const int q = (k8 + dk) & 127;
            const float* wp = wbase + q * 128;
            float4 w0 = *(const float4*)wp;
            float4 w1 = *(const float4*)(wp + 4);
            const float av = xv[dk] * sg;
            acc[0] += av * w0.x; acc[1] += av * w0.y; acc[2] += av * w0.z; acc[3] += av * w0.w;
            acc[4] += av * w1.x; acc[5] += av * w1.y; acc[6] += av * w1.z; acc[7] += av * w1.w;
        }
    }
    float s1p = 0.f, s2p = 0.f;
#pragma unroll
    for (int q = 0; q < 8; q++) {
        const int c = (cg << 3) + q;
        hT[(size_t)c * N_NODES + r] = f2bf_rtn(acc[q]);
        s1p += acc[q] * a[c];
        s2p += acc[q] * a[OUT_F + c];
    }
    atomicAdd(&s1b[rg], s1p);
    atomicAdd(&s2b[rg], s2p);
    __syncthreads();
    if (t < 16) { s1[blockIdx.x * 16 + t] = s1b[t]; s2[blockIdx.x * 16 + t] = s2b[t]; }
}

// ---------------- MFMA masked-softmax attention: barrier-free streaming, 8 waves ----------------
// grid (64, NSPLIT) x 512 thr. Block: 128 i (8 waves x 16) x 128 c over JSPAN=512 j.
// hT slice staged ONCE (130 KB LDS); adj streams to registers (1-chunk prefetch); no per-chunk barriers.
__global__ __launch_bounds__(512, 2) void k_att(const int* __restrict__ adj, const u16* __restrict__ hT,
                                                const float* __restrict__ s1, const float* __restrict__ s2,
                                                float* __restrict__ Opart, float* __restrict__ Lpart) {
    __shared__ u16 hs[128 * HSTR];    // 133120 B
    __shared__ float s2s[JSPAN];      // 2048 B
    const int t = threadIdx.x;
    const int lane = t & 63, wid = t >> 6;       // 8 waves
    const int quad = lane >> 4, n = lane & 15;
    const int i0 = blockIdx.x * TILE_I;
    const int jbase = blockIdx.y * JSPAN;
    const int i_lane = i0 + wid * 16 + n;        // A-frag m index
    const float s1v = s1[i_lane];

    if (t < 128) *(float4*)&s2s[t * 4] = *(const float4*)&s2[jbase + t * 4];
    // stage hT slice: 128 c-rows x 512 shorts; thread t -> row t>>2, quarter (t&3)*128 shorts
    {
        const int cr = t >> 2, off = (t & 3) * 128;
        const u16* src = hT + (size_t)cr * N_NODES + jbase + off;
        u16* dst = &hs[cr * HSTR + off];
#pragma unroll
        for (int v = 0; v < 16; v++)
            *(uint4*)(dst + v * 8) = *(const uint4*)(src + v * 8);
    }

    floatx4 acc[8];
#pragma unroll
    for (int ct = 0; ct < 8; ct++) acc[ct] = (floatx4){0.f, 0.f, 0.f, 0.f};
    float Lacc = 0.f;

    const int* adjp = adj + (size_t)i_lane * N_NODES + jbase;
    uint4 P[8];
#pragma unroll
    for (int ks = 0; ks < 4; ks++) {
        P[2 * ks]     = *(const uint4*)(adjp + ks * 32 + quad * 8);
        P[2 * ks + 1] = *(const uint4*)(adjp + ks * 32 + quad * 8 + 4);
    }
    __syncthreads();   // the ONLY barrier

#pragma unroll
    for (int k = 0; k < JSPAN / CH; k++) {       // 4 chunks, no barriers
        uint4 C[8];
#pragma unroll
        for (int v = 0; v < 8; v++) C[v] = P[v];
        if (k + 1 < JSPAN / CH) {
            const int* ap = adjp + (k + 1) * CH;
#pragma unroll
            for (int ks = 0; ks < 4; ks++) {
                P[2 * ks]     = *(const uint4*)(ap + ks * 32 + quad * 8);
                P[2 * ks + 1] = *(const uint4*)(ap + ks * 32 + quad * 8 + 4);
            }
        }
        short8 fa[4];
#pragma unroll
        for (int ks = 0; ks < 4; ks++) {
            const int jl = k * CH + ks * 32 + quad * 8;
            float4 sa = *(const float4*)&s2s[jl];
            float4 sb = *(const float4*)&s2s[jl + 4];
            const float sv[8] = {sa.x, sa.y, sa.z, sa.w, sb.x, sb.y, sb.z, sb.w};
            const u32 am[8] = {C[2*ks].x, C[2*ks].y, C[2*ks].z, C[2*ks].w,
                               C[2*ks+1].x, C[2*ks+1].y, C[2*ks+1].z, C[2*ks+1].w};
#pragma unroll
            for (int jj = 0; jj < 8; jj++) {
                float sc = s1v + sv[jj];
                sc = fmaxf(sc, LRELU_A * sc);
                float w = ((int)am[jj] > 0) ? __expf(sc - MSH) : 0.f;
                Lacc += w;
                fa[ks][jj] = (short)f2bf_rtn(w);
            }
        }
#pragma unroll
        for (int ks = 0; ks < 4; ks++) {
#pragma unroll
            for (int ct = 0; ct < 8; ct++) {
                short8 fb = *(const short8*)&hs[(ct * 16 + n) * HSTR + k * CH + ks * 32 + quad * 8];
                acc[ct] = __builtin_amdgcn_mfma_f32_16x16x32_bf16(fa[ks], fb, acc[ct], 0, 0, 0);
            }
        }
    }

    // L row-sum across quads (each lane's j's belong to row i_lane)
    Lacc += __shfl_xor(Lacc, 16, 64);
    Lacc += __shfl_xor(Lacc, 32, 64);
    if (lane < 16)
        Lpart[(size_t)blockIdx.y * N_NODES + i_lane] = Lacc;

    // store O partials (C layout: row = quad*4+reg, col = n)
    const size_t obase = (size_t)blockIdx.y * N_NODES * OUT_F;
#pragma unroll
    for (int ct = 0; ct < 8; ct++) {
#pragma unroll
        for (int r = 0; r < 4; r++) {
            const int i = i0 + wid * 16 + quad * 4 + r;
            Opart[obase + (size_t)i * OUT_F + ct * 16 + n] = acc[ct][r];
        }
    }
}

// ---------------- combine partials, normalize, column stats via atomics ----------------
// grid 512 x 256 thr; block = 16 i-rows
__global__ __launch_bounds__(256) void k_comb(const float* __restrict__ Opart, const float* __restrict__ Lpart,
                                              float* __restrict__ hp, float* __restrict__ cs, float* __restrict__ cq) {
    const int t = threadIdx.x;
    const int c = t & 127, half = t >> 7;
    const int ibase = blockIdx.x * 16;
    float sv = 0.f, sq = 0.f;
    for (int k = 0; k < 8; k++) {
        const int i = ibase + half + (k << 1);
        float o = 0.f, L = 0.f;
#pragma unroll
        for (int s = 0; s < NSPLIT; s++) {
            o += Opart[((size_t)s * N_NODES + i) * OUT_F + c];
            L += Lpart[(size_t)s * N_NODES + i];
        }
        float v = L > 0.f ? o / L : 0.f;
        hp[(size_t)i * OUT_F + c] = v;
        sv += v; sq += v * v;
    }
    __shared__ float red[256];
    red[t] = sv; __syncthreads();
    if (half == 0) atomicAdd(&cs[c], sv + red[t + 128]);
    __syncthreads(); red[t] = sq; __syncthreads();
    if (half == 0) atomicAdd(&cq[c], sq + red[t + 128]);
}

// ---------------- batchnorm + elu + f32 out ----------------
__global__ __launch_bounds__(256) void k_bn(const float* __restrict__ hp, const float* __restrict__ cs,
                                            const float* __restrict__ cq, const float* __restrict__ gamma,
                                            const float* __restrict__ beta, float* __restrict__ out) {
    const int idx = blockIdx.x * 256 + threadIdx.x;   // 1M
    const int c = idx & 127;
    const float mean = cs[c] * (1.f / N_NODES);
    const float var  = cq[c] * (1.f / N_NODES) - mean * mean;
    float x = (hp[idx] - mean) * rsqrtf(var + EPS_BN) * gamma[c] + beta[c];
    x = x > 0.f ? x : expm1f(x);
    out[idx] = x;
}

extern "C" void kernel_launch(void* const* d_in, const int* in_sizes, int n_in,
                              void* d_out, int out_size, void* d_ws, size_t ws_size,
                              hipStream_t stream) {
    (void)in_sizes; (void)n_in; (void)out_size; (void)ws_size;
    const float* inp   = (const float*)d_in[0];
    const int*   adj   = (const int*)d_in[1];
    const float* W     = (const float*)d_in[2];
    const float* a     = (const float*)d_in[3];
    const float* gamma = (const float*)d_in[4];
    const float* beta  = (const float*)d_in[5];
    float* out = (float*)d_out;

    char* wsb = (char*)d_ws;
    u16*   hT  = (u16*)wsb;    wsb += (size_t)OUT_F * N_NODES * 2;            // 2 MB
    float* s1  = (float*)wsb;  wsb += N_NODES * 4;
    float* s2  = (float*)wsb;  wsb += N_NODES * 4;
    float* Op  = (float*)wsb;  wsb += (size_t)NSPLIT * N_NODES * OUT_F * 4;   // 64 MB
    float* Lp  = (float*)wsb;  wsb += (size_t)NSPLIT * N_NODES * 4;
    float* hp  = (float*)wsb;  wsb += (size_t)N_NODES * OUT_F * 4;            // 4 MB
    float* cs  = (float*)wsb;  wsb += OUT_F * 4;
    float* cq  = (float*)wsb;  wsb += OUT_F * 4;

    hipLaunchKernelGGL(k_h,    dim3(512), dim3(256), 0, stream, inp, W, a, hT, s1, s2, cs, cq);
    hipLaunchKernelGGL(k_att,  dim3(64, NSPLIT), dim3(512), 0, stream, adj, hT, s1, s2, Op, Lp);
    hipLaunchKernelGGL(k_comb, dim3(512), dim3(256), 0, stream, Op, Lp, hp, cs, cq);
    hipLaunchKernelGGL(k_bn,   dim3(4096), dim3(256), 0, stream, hp, cs, cq, gamma, beta, out);
}

// Round 8
// 513.524 us; speedup vs baseline: 1.0527x; 1.0332x over previous
//
#include <hip/hip_runtime.h>
#include <hip/hip_bf16.h>
#include <math.h>

#define N_NODES 8192
#define IN_F    512
#define OUT_F   128
#define LRELU_A 0.2f
#define EPS_BN  1e-5f
#define MSH     40.0f                // static softmax shift (upper bound on lrelu(max s1+max s2))
#define NSPLIT  16
#define JSPAN   (N_NODES / NSPLIT)   // 512
#define TILE_I  128                  // 8 waves x 16 rows
#define CH      128                  // j per chunk (4 MFMA K-steps)
#define HSTR    520                  // LDS row stride in shorts (512 + 8 pad)
#define MWORDS  16                   // u32 mask words per row (512 bits)

typedef unsigned short u16;
typedef unsigned int   u32;
typedef unsigned long long u64;
typedef __attribute__((ext_vector_type(8))) short  short8;
typedef __attribute__((ext_vector_type(4))) float  floatx4;

__device__ __forceinline__ u16 f2bf_rtn(float x) {
    u32 u = __float_as_uint(x);
    return (u16)((u + 0x7fffu + ((u >> 16) & 1u)) >> 16);
}

// ---------------- h = input @ hamilton(W); W staged in LDS ----------------
// grid 512 x 256 thr; block = 16 rows x 128 cols; thread = 1 row x 8 cols.
__global__ __launch_bounds__(256) void k_h(const float* __restrict__ inp, const float* __restrict__ W,
                                           const float* __restrict__ a,
                                           u16* __restrict__ hT, float* __restrict__ s1, float* __restrict__ s2,
                                           float* __restrict__ cs, float* __restrict__ cq) {
    __shared__ float Wl[128 * 128];      // 64 KB: whole W
    __shared__ float s1b[16], s2b[16];
    const int t = threadIdx.x;
    if (t < 16) { s1b[t] = 0.f; s2b[t] = 0.f; }
    if (blockIdx.x == 0 && t < OUT_F) { cs[t] = 0.f; cq[t] = 0.f; }
#pragma unroll
    for (int i = 0; i < 16; i++) {
        const int idx = t * 4 + i * 1024;
        *(float4*)&Wl[idx] = *(const float4*)&W[idx];
    }
    __syncthreads();
    const int rg = t >> 4, cg = t & 15;
    const int r = blockIdx.x * 16 + rg;
    const int b = cg >> 2, cc0 = (cg & 3) * 8;
    const u32 NEGMASK = 0x284Eu;     // bit (b*4+p) set => sign -1
    float acc[8];
#pragma unroll
    for (int q = 0; q < 8; q++) acc[q] = 0.f;
    const float* row = inp + (size_t)r * IN_F;
    for (int k8 = 0; k8 < IN_F; k8 += 8) {
        const int p = k8 >> 7;
        const float sg = ((NEGMASK >> (b * 4 + p)) & 1u) ? -1.f : 1.f;
        const float* wbase = Wl + (b ^ p) * 32 + cc0;
        float4 x0 = *(const float4*)(row + k8);
        float4 x1 = *(const float4*)(row + k8 + 4);
        float xv[8] = {x0.x, x0.y, x0.z, x0.w, x1.x, x1.y, x1.z, x1.w};
#pragma unroll
        for (int dk = 0; dk < 8; dk++) {
            const int q = (k8 + dk) & 127;
            const float* wp = wbase + q * 128;
            float4 w0 = *(const float4*)wp;
            float4 w1 = *(const float4*)(wp + 4);
            const float av = xv[dk] * sg;
            acc[0] += av * w0.x; acc[1] += av * w0.y; acc[2] += av * w0.z; acc[3] += av * w0.w;
            acc[4] += av * w1.x; acc[5] += av * w1.y; acc[6] += av * w1.z; acc[7] += av * w1.w;
        }
    }
    float s1p = 0.f, s2p = 0.f;
#pragma unroll
    for (int q = 0; q < 8; q++) {
        const int c = (cg << 3) + q;
        hT[(size_t)c * N_NODES + r] = f2bf_rtn(acc[q]);
        s1p += acc[q] * a[c];
        s2p += acc[q] * a[OUT_F + c];
    }
    atomicAdd(&s1b[rg], s1p);
    atomicAdd(&s2b[rg], s2p);
    __syncthreads();
    if (t < 16) { s1[blockIdx.x * 16 + t] = s1b[t]; s2[blockIdx.x * 16 + t] = s2b[t]; }
}

// ---- ballot-pack one adj row (2 halves x 4 components) into 16 u32 mask words ----
__device__ __forceinline__ void pack_row(const uint4& h0, const uint4& h1, u32* mp, int lane) {
    u64 c0 = __ballot((int)h0.x > 0);
    u64 c1 = __ballot((int)h0.y > 0);
    u64 c2 = __ballot((int)h0.z > 0);
    u64 c3 = __ballot((int)h0.w > 0);
    u64 d0 = __ballot((int)h1.x > 0);
    u64 d1 = __ballot((int)h1.y > 0);
    u64 d2 = __ballot((int)h1.z > 0);
    u64 d3 = __ballot((int)h1.w > 0);
    if (lane == 0) {
        *(uint4*)(mp)      = make_uint4((u32)c0, (u32)(c0 >> 32), (u32)c1, (u32)(c1 >> 32));
        *(uint4*)(mp + 4)  = make_uint4((u32)c2, (u32)(c2 >> 32), (u32)c3, (u32)(c3 >> 32));
        *(uint4*)(mp + 8)  = make_uint4((u32)d0, (u32)(d0 >> 32), (u32)d1, (u32)(d1 >> 32));
        *(uint4*)(mp + 12) = make_uint4((u32)d2, (u32)(d2 >> 32), (u32)d3, (u32)(d3 >> 32));
    }
}

// ---------------- MFMA masked-softmax attention: coalesced adj -> bitmask -> global-free loop ----------------
// grid (64, NSPLIT) x 512 thr. Block: 128 i (8 waves x 16) x 128 c over JSPAN=512 j.
__global__ __launch_bounds__(512, 2) void k_att(const int* __restrict__ adj, const u16* __restrict__ hT,
                                                const float* __restrict__ s1, const float* __restrict__ s2,
                                                float* __restrict__ Opart, float* __restrict__ Lpart) {
    __shared__ u16 hs[128 * HSTR];          // 133120 B
    __shared__ float s2s[JSPAN];            // 2048 B
    __shared__ u32 mk[8 * 16 * MWORDS];     // 8192 B  (wave-private rows)
    const int t = threadIdx.x;
    const int lane = t & 63, wid = t >> 6;
    const int quad = lane >> 4, n = lane & 15;
    const int i0 = blockIdx.x * TILE_I;
    const int jbase = blockIdx.y * JSPAN;
    const int i_lane = i0 + wid * 16 + n;   // A-frag m index
    const float s1v = s1[i_lane];

    if (t < 128) *(float4*)&s2s[t * 4] = *(const float4*)&s2[jbase + t * 4];
    // stage hT slice coalesced: thread t -> c-row t>>2, quarter (t&3)*128 shorts
    {
        const int cr = t >> 2, off = (t & 3) * 128;
        const u16* src = hT + (size_t)cr * N_NODES + jbase + off;
        u16* dst = &hs[cr * HSTR + off];
#pragma unroll
        for (int v = 0; v < 16; v++)
            *(uint4*)(dst + v * 8) = *(const uint4*)(src + v * 8);
    }

    // ---- adj -> bitmask phase: wave loads its own 16 rows, 1 KB contiguous per instruction ----
    {
        const int* abase = adj + (size_t)(i0 + wid * 16) * N_NODES + jbase + lane * 4;
        u32* mwp = &mk[(wid * 16) * MWORDS];
        uint4 P0[8], P1[8];
#pragma unroll
        for (int rr = 0; rr < 4; rr++) {
            P0[2 * rr]     = *(const uint4*)(abase + (size_t)rr * N_NODES);
            P0[2 * rr + 1] = *(const uint4*)(abase + (size_t)rr * N_NODES + 256);
        }
#pragma unroll
        for (int rr = 0; rr < 4; rr++) {
            P1[2 * rr]     = *(const uint4*)(abase + (size_t)(4 + rr) * N_NODES);
            P1[2 * rr + 1] = *(const uint4*)(abase + (size_t)(4 + rr) * N_NODES + 256);
        }
#pragma unroll
        for (int rr = 0; rr < 4; rr++) pack_row(P0[2 * rr], P0[2 * rr + 1], mwp + rr * MWORDS, lane);
#pragma unroll
        for (int rr = 0; rr < 4; rr++) {
            P0[2 * rr]     = *(const uint4*)(abase + (size_t)(8 + rr) * N_NODES);
            P0[2 * rr + 1] = *(const uint4*)(abase + (size_t)(8 + rr) * N_NODES + 256);
        }
#pragma unroll
        for (int rr = 0; rr < 4; rr++) pack_row(P1[2 * rr], P1[2 * rr + 1], mwp + (4 + rr) * MWORDS, lane);
#pragma unroll
        for (int rr = 0; rr < 4; rr++) {
            P1[2 * rr]     = *(const uint4*)(abase + (size_t)(12 + rr) * N_NODES);
            P1[2 * rr + 1] = *(const uint4*)(abase + (size_t)(12 + rr) * N_NODES + 256);
        }
#pragma unroll
        for (int rr = 0; rr < 4; rr++) pack_row(P0[2 * rr], P0[2 * rr + 1], mwp + (8 + rr) * MWORDS, lane);
#pragma unroll
        for (int rr = 0; rr < 4; rr++) pack_row(P1[2 * rr], P1[2 * rr + 1], mwp + (12 + rr) * MWORDS, lane);
    }
    __syncthreads();   // the ONLY barrier (hT + masks committed)

    // my row's mask words
    u32 m32[16];
    {
        const u32* mp = &mk[(wid * 16 + n) * MWORDS];
        *(uint4*)&m32[0]  = *(const uint4*)(mp);
        *(uint4*)&m32[4]  = *(const uint4*)(mp + 4);
        *(uint4*)&m32[8]  = *(const uint4*)(mp + 8);
        *(uint4*)&m32[12] = *(const uint4*)(mp + 12);
    }

    floatx4 acc[8];
#pragma unroll
    for (int ct = 0; ct < 8; ct++) acc[ct] = (floatx4){0.f, 0.f, 0.f, 0.f};
    float Lacc = 0.f;

#pragma unroll
    for (int k = 0; k < JSPAN / CH; k++) {       // 4 chunks, zero global traffic
        short8 fa[4];
#pragma unroll
        for (int ks = 0; ks < 4; ks++) {
            const int jl = k * CH + ks * 32 + quad * 8;
            float4 sa = *(const float4*)&s2s[jl];
            float4 sb = *(const float4*)&s2s[jl + 4];
            const float sv[8] = {sa.x, sa.y, sa.z, sa.w, sb.x, sb.y, sb.z, sb.w};
            const int bit32 = ks * 8 + quad * 2;
#pragma unroll
            for (int jj = 0; jj < 8; jj++) {
                const u32 word = m32[(k >> 1) * 8 + (jj & 3) * 2 + (k & 1)];
                const u32 mbit = (word >> (bit32 + (jj >> 2))) & 1u;
                float sc = s1v + sv[jj];
                sc = fmaxf(sc, LRELU_A * sc);
                float w = mbit ? __expf(sc - MSH) : 0.f;
                Lacc += w;
                fa[ks][jj] = (short)f2bf_rtn(w);
            }
        }
#pragma unroll
        for (int ks = 0; ks < 4; ks++) {
#pragma unroll
            for (int ct = 0; ct < 8; ct++) {
                short8 fb = *(const short8*)&hs[(ct * 16 + n) * HSTR + k * CH + ks * 32 + quad * 8];
                acc[ct] = __builtin_amdgcn_mfma_f32_16x16x32_bf16(fa[ks], fb, acc[ct], 0, 0, 0);
            }
        }
    }

    // L row-sum across quads
    Lacc += __shfl_xor(Lacc, 16, 64);
    Lacc += __shfl_xor(Lacc, 32, 64);
    if (lane < 16)
        Lpart[(size_t)blockIdx.y * N_NODES + i_lane] = Lacc;

    // store O partials (C layout: row = quad*4+reg, col = n)
    const size_t obase = (size_t)blockIdx.y * N_NODES * OUT_F;
#pragma unroll
    for (int ct = 0; ct < 8; ct++) {
#pragma unroll
        for (int r = 0; r < 4; r++) {
            const int i = i0 + wid * 16 + quad * 4 + r;
            Opart[obase + (size_t)i * OUT_F + ct * 16 + n] = acc[ct][r];
        }
    }
}

// ---------------- combine partials, normalize, column stats via atomics ----------------
// grid 512 x 256 thr; block = 16 i-rows
__global__ __launch_bounds__(256) void k_comb(const float* __restrict__ Opart, const float* __restrict__ Lpart,
                                              float* __restrict__ hp, float* __restrict__ cs, float* __restrict__ cq) {
    const int t = threadIdx.x;
    const int c = t & 127, half = t >> 7;
    const int ibase = blockIdx.x * 16;
    float sv = 0.f, sq = 0.f;
    for (int k = 0; k < 8; k++) {
        const int i = ibase + half + (k << 1);
        float o = 0.f, L = 0.f;
#pragma unroll
        for (int s = 0; s < NSPLIT; s++) {
            o += Opart[((size_t)s * N_NODES + i) * OUT_F + c];
            L += Lpart[(size_t)s * N_NODES + i];
        }
        float v = L > 0.f ? o / L : 0.f;
        hp[(size_t)i * OUT_F + c] = v;
        sv += v; sq += v * v;
    }
    __shared__ float red[256];
    red[t] = sv; __syncthreads();
    if (half == 0) atomicAdd(&cs[c], sv + red[t + 128]);
    __syncthreads(); red[t] = sq; __syncthreads();
    if (half == 0) atomicAdd(&cq[c], sq + red[t + 128]);
}

// ---------------- batchnorm + elu + f32 out ----------------
__global__ __launch_bounds__(256) void k_bn(const float* __restrict__ hp, const float* __restrict__ cs,
                                            const float* __restrict__ cq, const float* __restrict__ gamma,
                                            const float* __restrict__ beta, float* __restrict__ out) {
    const int idx = blockIdx.x * 256 + threadIdx.x;   // 1M
    const int c = idx & 127;
    const float mean = cs[c] * (1.f / N_NODES);
    const float var  = cq[c] * (1.f / N_NODES) - mean * mean;
    float x = (hp[idx] - mean) * rsqrtf(var + EPS_BN) * gamma[c] + beta[c];
    x = x > 0.f ? x : expm1f(x);
    out[idx] = x;
}

extern "C" void kernel_launch(void* const* d_in, const int* in_sizes, int n_in,
                              void* d_out, int out_size, void* d_ws, size_t ws_size,
                              hipStream_t stream) {
    (void)in_sizes; (void)n_in; (void)out_size; (void)ws_size;
    const float* inp   = (const float*)d_in[0];
    const int*   adj   = (const int*)d_in[1];
    const float* W     = (const float*)d_in[2];
    const float* a     = (const float*)d_in[3];
    const float* gamma = (const float*)d_in[4];
    const float* beta  = (const float*)d_in[5];
    float* out = (float*)d_out;

    char* wsb = (char*)d_ws;
    u16*   hT  = (u16*)wsb;    wsb += (size_t)OUT_F * N_NODES * 2;            // 2 MB
    float* s1  = (float*)wsb;  wsb += N_NODES * 4;
    float* s2  = (float*)wsb;  wsb += N_NODES * 4;
    float* Op  = (float*)wsb;  wsb += (size_t)NSPLIT * N_NODES * OUT_F * 4;   // 64 MB
    float* Lp  = (float*)wsb;  wsb += (size_t)NSPLIT * N_NODES * 4;
    float* hp  = (float*)wsb;  wsb += (size_t)N_NODES * OUT_F * 4;            // 4 MB
    float* cs  = (float*)wsb;  wsb += OUT_F * 4;
    float* cq  = (float*)wsb;  wsb += OUT_F * 4;

    hipLaunchKernelGGL(k_h,    dim3(512), dim3(256), 0, stream, inp, W, a, hT, s1, s2, cs, cq);
    hipLaunchKernelGGL(k_att,  dim3(64, NSPLIT), dim3(512), 0, stream, adj, hT, s1, s2, Op, Lp);
    hipLaunchKernelGGL(k_comb, dim3(512), dim3(256), 0, stream, Op, Lp, hp, cs, cq);
    hipLaunchKernelGGL(k_bn,   dim3(4096), dim3(256), 0, stream, hp, cs, cq, gamma, beta, out);
}